// Round 2
// baseline (2459.249 us; speedup 1.0000x reference)
//
#include <hip/hip_runtime.h>
#include <hip/hip_bf16.h>

#define N_NODES 200000
#define N_EDGES 600000
#define EMB 128
#define HID 128
#define N_RELS 64
#define N_MOTIFS 512
#define N_CENTERS 256
#define NCLS 16

typedef unsigned short u16;
typedef __attribute__((ext_vector_type(8))) short short8;   // 8 x bf16 MFMA frag
typedef __attribute__((ext_vector_type(4))) float f32x4;
typedef __attribute__((ext_vector_type(4))) unsigned short u16x4;

__device__ __forceinline__ float bf2f(u16 u) {
    unsigned int i = ((unsigned int)u) << 16;
    float f; __builtin_memcpy(&f, &i, 4); return f;
}
__device__ __forceinline__ u16 f2bf(float f) {
    unsigned int x; __builtin_memcpy(&x, &f, 4);
    x += 0x7fffu + ((x >> 16) & 1u);          // RNE
    return (u16)(x >> 16);
}

// bf16 weight-table offsets (elements) inside ws
#define O_LINW   0
#define O_LINB   16384
#define O_C1W    16512
#define O_C1B    32896
#define O_C2W    33024
#define O_C2B    49408
#define O_EW     49536
#define O_EB     65920
#define O_MW     65984
#define O_MB     131520
#define O_NW     132032
#define O_NB     134080
#define N_WB     134096

// ---------------------------------------------------------------------------
// convert all weight arrays f32 -> bf16 into one table
// ---------------------------------------------------------------------------
__global__ void k_cvt(const float* __restrict__ lw, const float* __restrict__ lb,
                      const float* __restrict__ c1w, const float* __restrict__ c1b,
                      const float* __restrict__ c2w, const float* __restrict__ c2b,
                      const float* __restrict__ ew, const float* __restrict__ eb,
                      const float* __restrict__ mw, const float* __restrict__ mb,
                      const float* __restrict__ nw, const float* __restrict__ nb,
                      u16* __restrict__ wb)
{
    const int t = blockIdx.x * 256 + threadIdx.x;
    if (t >= N_WB) return;
    float v;
    if      (t < O_LINB) v = lw[t - O_LINW];
    else if (t < O_C1W)  v = lb[t - O_LINB];
    else if (t < O_C1B)  v = c1w[t - O_C1W];
    else if (t < O_C2W)  v = c1b[t - O_C1B];
    else if (t < O_C2B)  v = c2w[t - O_C2W];
    else if (t < O_EW)   v = c2b[t - O_C2B];
    else if (t < O_EB)   v = ew[t - O_EW];
    else if (t < O_MW)   v = eb[t - O_EB];
    else if (t < O_MB)   v = mw[t - O_MW];
    else if (t < O_NW)   v = mb[t - O_MB];
    else if (t < O_NB)   v = nw[t - O_NW];
    else                 v = nb[t - O_NB];
    wb[t] = f2bf(v);
}

// ---------------------------------------------------------------------------
// rel_lin[r][h] = sum_k rel_emb[r][k] * lin_w[h][k] + lin_b[h]   (all f32)
// ---------------------------------------------------------------------------
__global__ void k_rel(const float* __restrict__ rel_emb, const float* __restrict__ lw,
                      const float* __restrict__ lb, float* __restrict__ rel_lin)
{
    __shared__ float e[EMB];
    const int r = blockIdx.x, h = threadIdx.x;
    e[h] = rel_emb[r * EMB + h];
    __syncthreads();
    const float* wr = lw + (size_t)h * EMB;
    float acc = lb[h];
    #pragma unroll
    for (int k0 = 0; k0 < EMB; k0 += 4) {
        f32x4 wv = *(const f32x4*)(wr + k0);
        #pragma unroll
        for (int j = 0; j < 4; ++j) acc += e[k0 + j] * wv[j];
    }
    rel_lin[r * HID + h] = acc;
}

// ---------------------------------------------------------------------------
// x0 = bf16( node_emb[ids] @ lin_w^T + lin_b )   (emb f32, weights bf16 table)
// ---------------------------------------------------------------------------
__global__ __launch_bounds__(256) void k_lin(
    const float* __restrict__ emb, const int* __restrict__ ids,
    const u16* __restrict__ w, const u16* __restrict__ bias,
    u16* __restrict__ out)
{
    const int wid = threadIdx.x >> 6, lane = threadIdx.x & 63;
    const int r15 = lane & 15, kg = (lane >> 4) * 8;
    const int arow = blockIdx.x * 64 + wid * 16 + r15;
    const int srow = ids[arow];
    const float* ar = emb + (size_t)srow * EMB + kg;
    short8 a[4];
    #pragma unroll
    for (int kk = 0; kk < 4; ++kk) {
        f32x4 a0 = *(const f32x4*)(ar + kk * 32);
        f32x4 a1 = *(const f32x4*)(ar + kk * 32 + 4);
        short8 t;
        #pragma unroll
        for (int j = 0; j < 4; ++j) { t[j] = (short)f2bf(a0[j]); t[4 + j] = (short)f2bf(a1[j]); }
        a[kk] = t;
    }
    f32x4 acc[8];
    #pragma unroll
    for (int nb = 0; nb < 8; ++nb) acc[nb] = (f32x4){0.f, 0.f, 0.f, 0.f};
    #pragma unroll
    for (int nb = 0; nb < 8; ++nb) {
        const u16* wr = w + (size_t)(nb * 16 + r15) * EMB + kg;
        #pragma unroll
        for (int kk = 0; kk < 4; ++kk) {
            short8 bv = *(const short8*)(wr + kk * 32);
            acc[nb] = __builtin_amdgcn_mfma_f32_16x16x32_bf16(a[kk], bv, acc[nb], 0, 0, 0);
        }
    }
    const int ob = blockIdx.x * 64 + wid * 16 + (lane >> 4) * 4;
    #pragma unroll
    for (int nb = 0; nb < 8; ++nb) {
        const int col = nb * 16 + r15;
        const float bn = bf2f(bias[col]);
        #pragma unroll
        for (int r = 0; r < 4; ++r)
            out[(size_t)(ob + r) * HID + col] = f2bf(acc[nb][r] + bn);
    }
}

// ---------------------------------------------------------------------------
// message scatter: agg[dst][c] += relu(x[src][c] + rel_lin[rid][c])
// ---------------------------------------------------------------------------
__global__ __launch_bounds__(256) void k_msg(
    const u16* __restrict__ x, const float* __restrict__ rel_lin,
    const int* __restrict__ src, const int* __restrict__ dst,
    const int* __restrict__ rid, float* __restrict__ agg)
{
    const int t = blockIdx.x * 256 + threadIdx.x;
    const int e = t >> 5;
    const int c = (t & 31) * 4;
    if (e >= N_EDGES) return;
    const int s = src[e], d = dst[e], r = rid[e];
    u16x4 xv = *(const u16x4*)(x + (size_t)s * HID + c);
    f32x4 rv = *(const f32x4*)(rel_lin + r * HID + c);
    float* ap = agg + (size_t)d * HID + c;
    #pragma unroll
    for (int j = 0; j < 4; ++j) {
        float m = bf2f((u16)xv[j]) + rv[j];
        m = fmaxf(m, 0.f);
        atomicAdd(ap + j, m);
    }
}

// ---------------------------------------------------------------------------
// conv GEMM: out = act( bf16(agg + x) @ w^T + b ),  act = relu if do_relu
// ---------------------------------------------------------------------------
__global__ __launch_bounds__(256) void k_conv(
    const float* __restrict__ agg, const u16* __restrict__ x,
    const u16* __restrict__ w, const u16* __restrict__ bias,
    u16* __restrict__ out, const int do_relu)
{
    const int wid = threadIdx.x >> 6, lane = threadIdx.x & 63;
    const int r15 = lane & 15, kg = (lane >> 4) * 8;
    const int arow = blockIdx.x * 64 + wid * 16 + r15;
    const float* ar = agg + (size_t)arow * HID + kg;
    const u16* xr = x + (size_t)arow * HID + kg;
    short8 a[4];
    #pragma unroll
    for (int kk = 0; kk < 4; ++kk) {
        f32x4 g0 = *(const f32x4*)(ar + kk * 32);
        f32x4 g1 = *(const f32x4*)(ar + kk * 32 + 4);
        short8 xv = *(const short8*)(xr + kk * 32);
        short8 t;
        #pragma unroll
        for (int j = 0; j < 4; ++j) t[j] = (short)f2bf(g0[j] + bf2f((u16)xv[j]));
        #pragma unroll
        for (int j = 0; j < 4; ++j) t[4 + j] = (short)f2bf(g1[j] + bf2f((u16)xv[4 + j]));
        a[kk] = t;
    }
    f32x4 acc[8];
    #pragma unroll
    for (int nb = 0; nb < 8; ++nb) acc[nb] = (f32x4){0.f, 0.f, 0.f, 0.f};
    #pragma unroll
    for (int nb = 0; nb < 8; ++nb) {
        const u16* wr = w + (size_t)(nb * 16 + r15) * HID + kg;
        #pragma unroll
        for (int kk = 0; kk < 4; ++kk) {
            short8 bv = *(const short8*)(wr + kk * 32);
            acc[nb] = __builtin_amdgcn_mfma_f32_16x16x32_bf16(a[kk], bv, acc[nb], 0, 0, 0);
        }
    }
    const int ob = blockIdx.x * 64 + wid * 16 + (lane >> 4) * 4;
    #pragma unroll
    for (int nb = 0; nb < 8; ++nb) {
        const int col = nb * 16 + r15;
        const float bn = bf2f(bias[col]);
        #pragma unroll
        for (int r = 0; r < 4; ++r) {
            float v = acc[nb][r] + bn;
            if (do_relu) v = fmaxf(v, 0.f);
            out[(size_t)(ob + r) * HID + col] = f2bf(v);
        }
    }
}

// ---------------------------------------------------------------------------
// edge head: out[e][n] = x2[src].ew[n][0:128] + x2[dst].ew[n][128:256] + eb[n]
// f32 output
// ---------------------------------------------------------------------------
__global__ __launch_bounds__(256) void k_edge(
    const u16* __restrict__ x2, const int* __restrict__ src, const int* __restrict__ dst,
    const u16* __restrict__ ew, const u16* __restrict__ eb, float* __restrict__ out)
{
    const int wid = threadIdx.x >> 6, lane = threadIdx.x & 63;
    const int r15 = lane & 15, kg = (lane >> 4) * 8;
    const int erow = blockIdx.x * 64 + wid * 16 + r15;
    const int s = src[erow], d = dst[erow];
    const u16* xs = x2 + (size_t)s * HID + kg;
    const u16* xd = x2 + (size_t)d * HID + kg;
    short8 a[8];
    #pragma unroll
    for (int kk = 0; kk < 4; ++kk) a[kk] = *(const short8*)(xs + kk * 32);
    #pragma unroll
    for (int kk = 0; kk < 4; ++kk) a[4 + kk] = *(const short8*)(xd + kk * 32);
    f32x4 acc[4];
    #pragma unroll
    for (int nb = 0; nb < 4; ++nb) acc[nb] = (f32x4){0.f, 0.f, 0.f, 0.f};
    #pragma unroll
    for (int nb = 0; nb < 4; ++nb) {
        const u16* wr = ew + (size_t)(nb * 16 + r15) * 256 + kg;
        #pragma unroll
        for (int kk = 0; kk < 8; ++kk) {
            short8 bv = *(const short8*)(wr + kk * 32);
            acc[nb] = __builtin_amdgcn_mfma_f32_16x16x32_bf16(a[kk], bv, acc[nb], 0, 0, 0);
        }
    }
    const int ob = blockIdx.x * 64 + wid * 16 + (lane >> 4) * 4;
    #pragma unroll
    for (int nb = 0; nb < 4; ++nb) {
        const int col = nb * 16 + r15;
        const float bn = bf2f(eb[col]);
        #pragma unroll
        for (int r = 0; r < 4; ++r)
            out[(size_t)(ob + r) * 64 + col] = acc[nb][r] + bn;
    }
}

// ---------------------------------------------------------------------------
// motif head: out[c][m] = x2[center[c]] . mw[m] + mb[m]   (f32 out)
// ---------------------------------------------------------------------------
__global__ void k_motif(const u16* __restrict__ x2, const int* __restrict__ centers,
                        const u16* __restrict__ mw, const u16* __restrict__ mb,
                        float* __restrict__ out)
{
    __shared__ float xs[HID];
    const int c = blockIdx.x, m = threadIdx.x;
    if (m < HID) xs[m] = bf2f(x2[(size_t)centers[c] * HID + m]);
    __syncthreads();
    const u16* wr = mw + (size_t)m * HID;
    float acc = bf2f(mb[m]);
    #pragma unroll
    for (int k0 = 0; k0 < HID; k0 += 8) {
        short8 wv = *(const short8*)(wr + k0);
        #pragma unroll
        for (int j = 0; j < 8; ++j) acc += xs[k0 + j] * bf2f((u16)wv[j]);
    }
    out[(size_t)c * N_MOTIFS + m] = acc;
}

// ---------------------------------------------------------------------------
// node head: out[i][n] = x2[i] . nw[n] + nb[n]   (f32 out)
// ---------------------------------------------------------------------------
__global__ __launch_bounds__(256) void k_node(
    const u16* __restrict__ x2, const u16* __restrict__ nw,
    const u16* __restrict__ nbias, float* __restrict__ out)
{
    const int wid = threadIdx.x >> 6, lane = threadIdx.x & 63;
    const int r15 = lane & 15, kg = (lane >> 4) * 8;
    const int arow = blockIdx.x * 64 + wid * 16 + r15;
    const u16* xr = x2 + (size_t)arow * HID + kg;
    const u16* wr = nw + (size_t)r15 * HID + kg;
    f32x4 acc = (f32x4){0.f, 0.f, 0.f, 0.f};
    #pragma unroll
    for (int kk = 0; kk < 4; ++kk) {
        short8 a = *(const short8*)(xr + kk * 32);
        short8 bv = *(const short8*)(wr + kk * 32);
        acc = __builtin_amdgcn_mfma_f32_16x16x32_bf16(a, bv, acc, 0, 0, 0);
    }
    const int ob = blockIdx.x * 64 + wid * 16 + (lane >> 4) * 4;
    const float bn = bf2f(nbias[r15]);
    #pragma unroll
    for (int r = 0; r < 4; ++r)
        out[(size_t)(ob + r) * NCLS + r15] = acc[r] + bn;
}

// ---------------------------------------------------------------------------
extern "C" void kernel_launch(void* const* d_in, const int* in_sizes, int n_in,
                              void* d_out, int out_size, void* d_ws, size_t ws_size,
                              hipStream_t stream)
{
    const float* node_emb = (const float*)d_in[0];
    const float* rel_emb  = (const float*)d_in[1];
    const float* lin_w    = (const float*)d_in[2];
    const float* lin_b    = (const float*)d_in[3];
    const float* conv1_w  = (const float*)d_in[4];
    const float* conv1_b  = (const float*)d_in[5];
    const float* conv2_w  = (const float*)d_in[6];
    const float* conv2_b  = (const float*)d_in[7];
    const float* edge_w   = (const float*)d_in[8];
    const float* edge_b   = (const float*)d_in[9];
    const float* motif_w  = (const float*)d_in[10];
    const float* motif_b  = (const float*)d_in[11];
    const float* node_w   = (const float*)d_in[12];
    const float* node_b   = (const float*)d_in[13];
    const int* node_ids = (const int*)d_in[14];
    const int* rel_ids  = (const int*)d_in[15];
    const int* centers  = (const int*)d_in[16];
    const int* src      = (const int*)d_in[17];             // edge_index[0]
    const int* dst      = ((const int*)d_in[17]) + N_EDGES; // edge_index[1]

    // workspace layout (~205.3 MB):
    //   [0, 32KB)            rel_lin f32 [64][128]
    //   [32KB, +268KB)       wb: bf16 weight table (134096 elems)
    //   [512KB, +51.2MB)     x0 bf16  (aliased by x2; x0 dead after conv1)
    //   [+51.2MB, +51.2MB)   x1 bf16
    //   [+102.4MB, +102.4MB) agg f32 [N][128]
    char* ws = (char*)d_ws;
    float* rel_lin = (float*)ws;
    u16*   wb      = (u16*)(ws + 32768);
    u16*   x0      = (u16*)(ws + 524288);
    u16*   x1      = (u16*)(ws + 524288 + 51200000);
    float* agg     = (float*)(ws + 524288 + 2 * 51200000);
    u16*   x2      = x0;

    float* out_edge  = (float*)d_out;                            // [600000][64]
    float* out_motif = out_edge + (size_t)N_EDGES * 64;          // [256][512]
    float* out_node  = out_motif + (size_t)N_CENTERS * N_MOTIFS; // [200000][16]

    const size_t agg_bytes = (size_t)N_NODES * HID * sizeof(float);

    k_cvt<<<(N_WB + 255) / 256, 256, 0, stream>>>(
        lin_w, lin_b, conv1_w, conv1_b, conv2_w, conv2_b,
        edge_w, edge_b, motif_w, motif_b, node_w, node_b, wb);
    hipMemsetAsync(agg, 0, agg_bytes, stream);
    k_rel<<<N_RELS, 128, 0, stream>>>(rel_emb, lin_w, lin_b, rel_lin);
    k_lin<<<N_NODES / 64, 256, 0, stream>>>(node_emb, node_ids, wb + O_LINW, wb + O_LINB, x0);
    k_msg<<<(N_EDGES * 32) / 256, 256, 0, stream>>>(x0, rel_lin, src, dst, rel_ids, agg);
    k_conv<<<N_NODES / 64, 256, 0, stream>>>(agg, x0, wb + O_C1W, wb + O_C1B, x1, 1);
    hipMemsetAsync(agg, 0, agg_bytes, stream);
    k_msg<<<(N_EDGES * 32) / 256, 256, 0, stream>>>(x1, rel_lin, src, dst, rel_ids, agg);
    k_conv<<<N_NODES / 64, 256, 0, stream>>>(agg, x1, wb + O_C2W, wb + O_C2B, x2, 0);
    k_edge<<<N_EDGES / 64, 256, 0, stream>>>(x2, src, dst, wb + O_EW, wb + O_EB, out_edge);
    k_motif<<<N_CENTERS, N_MOTIFS, 0, stream>>>(x2, centers, wb + O_MW, wb + O_MB, out_motif);
    k_node<<<N_NODES / 64, 256, 0, stream>>>(x2, wb + O_NW, wb + O_NB, out_node);
}

// Round 3
// 615.434 us; speedup vs baseline: 3.9960x; 3.9960x over previous
//
#include <hip/hip_runtime.h>
#include <hip/hip_bf16.h>

#define N_NODES 200000
#define N_EDGES 600000
#define EMB 128
#define HID 128
#define N_RELS 64
#define N_MOTIFS 512
#define N_CENTERS 256
#define NCLS 16

#define SCAN_C 512
#define NB_SCAN ((N_NODES + SCAN_C - 1) / SCAN_C)   // 391

typedef unsigned short u16;
typedef __attribute__((ext_vector_type(8))) short short8;   // 8 x bf16
typedef __attribute__((ext_vector_type(4))) float f32x4;
typedef __attribute__((ext_vector_type(4))) unsigned short u16x4;

__device__ __forceinline__ float bf2f(u16 u) {
    unsigned int i = ((unsigned int)u) << 16;
    float f; __builtin_memcpy(&f, &i, 4); return f;
}
__device__ __forceinline__ u16 f2bf(float f) {
    unsigned int x; __builtin_memcpy(&x, &f, 4);
    x += 0x7fffu + ((x >> 16) & 1u);          // RNE
    return (u16)(x >> 16);
}

// bf16 weight-table offsets (elements) inside ws
#define O_LINW   0
#define O_LINB   16384
#define O_C1W    16512
#define O_C1B    32896
#define O_C2W    33024
#define O_C2B    49408
#define O_EW     49536
#define O_EB     65920
#define O_MW     65984
#define O_MB     131520
#define O_NW     132032
#define O_NB     134080
#define N_WB     134096

// ---------------------------------------------------------------------------
__global__ void k_cvt(const float* __restrict__ lw, const float* __restrict__ lb,
                      const float* __restrict__ c1w, const float* __restrict__ c1b,
                      const float* __restrict__ c2w, const float* __restrict__ c2b,
                      const float* __restrict__ ew, const float* __restrict__ eb,
                      const float* __restrict__ mw, const float* __restrict__ mb,
                      const float* __restrict__ nw, const float* __restrict__ nb,
                      u16* __restrict__ wb)
{
    const int t = blockIdx.x * 256 + threadIdx.x;
    if (t >= N_WB) return;
    float v;
    if      (t < O_LINB) v = lw[t - O_LINW];
    else if (t < O_C1W)  v = lb[t - O_LINB];
    else if (t < O_C1B)  v = c1w[t - O_C1W];
    else if (t < O_C2W)  v = c1b[t - O_C1B];
    else if (t < O_C2B)  v = c2w[t - O_C2W];
    else if (t < O_EW)   v = c2b[t - O_C2B];
    else if (t < O_EB)   v = ew[t - O_EW];
    else if (t < O_MW)   v = eb[t - O_EB];
    else if (t < O_MB)   v = mw[t - O_MW];
    else if (t < O_NW)   v = mb[t - O_MB];
    else if (t < O_NB)   v = nw[t - O_NW];
    else                 v = nb[t - O_NB];
    wb[t] = f2bf(v);
}

// ---------------------------------------------------------------------------
// rel_lin[r][h] = rel_emb[r] . lin_w[h] + lin_b[h]   (all f32)
// ---------------------------------------------------------------------------
__global__ void k_rel(const float* __restrict__ rel_emb, const float* __restrict__ lw,
                      const float* __restrict__ lb, float* __restrict__ rel_lin)
{
    __shared__ float e[EMB];
    const int r = blockIdx.x, h = threadIdx.x;
    e[h] = rel_emb[r * EMB + h];
    __syncthreads();
    const float* wr = lw + (size_t)h * EMB;
    float acc = lb[h];
    #pragma unroll
    for (int k0 = 0; k0 < EMB; k0 += 4) {
        f32x4 wv = *(const f32x4*)(wr + k0);
        #pragma unroll
        for (int j = 0; j < 4; ++j) acc += e[k0 + j] * wv[j];
    }
    rel_lin[r * HID + h] = acc;
}

// ---------------------------------------------------------------------------
// CSR build: histogram, 3-kernel scan, fill
// ---------------------------------------------------------------------------
__global__ void k_hist(const int* __restrict__ dst, int* __restrict__ deg)
{
    const int e = blockIdx.x * 256 + threadIdx.x;
    if (e < N_EDGES) atomicAdd(&deg[dst[e]], 1);
}

__global__ void k_scan1(const int* __restrict__ deg, int* __restrict__ bsum)
{
    __shared__ int sd[256];
    const int t = threadIdx.x, base = blockIdx.x * SCAN_C;
    int v = 0;
    int i0 = base + t, i1 = base + 256 + t;
    if (i0 < N_NODES) v += deg[i0];
    if (i1 < N_NODES) v += deg[i1];
    sd[t] = v; __syncthreads();
    for (int s = 128; s > 0; s >>= 1) {
        if (t < s) sd[t] += sd[t + s];
        __syncthreads();
    }
    if (t == 0) bsum[blockIdx.x] = sd[0];
}

__global__ void k_scan2(int* __restrict__ bsum, int* __restrict__ row_ptr)
{
    __shared__ int sh[512];
    const int t = threadIdx.x;
    int v = (t < NB_SCAN) ? bsum[t] : 0;
    sh[t] = v;
    for (int off = 1; off < 512; off <<= 1) {
        __syncthreads();
        int a = (t >= off) ? sh[t - off] : 0;
        __syncthreads();
        sh[t] += a;
    }
    __syncthreads();
    if (t < NB_SCAN) bsum[t] = sh[t] - v;         // exclusive
    if (t == 511) row_ptr[N_NODES] = sh[511];     // total = E
}

__global__ void k_scan3(const int* __restrict__ deg, const int* __restrict__ bsum,
                        int* __restrict__ row_ptr)
{
    __shared__ int sh[256];
    const int t = threadIdx.x, base = blockIdx.x * SCAN_C;
    const int i0 = base + 2 * t, i1 = i0 + 1;
    int d0 = (i0 < N_NODES) ? deg[i0] : 0;
    int d1 = (i1 < N_NODES) ? deg[i1] : 0;
    int p = d0 + d1;
    sh[t] = p;
    for (int off = 1; off < 256; off <<= 1) {
        __syncthreads();
        int a = (t >= off) ? sh[t - off] : 0;
        __syncthreads();
        sh[t] += a;
    }
    __syncthreads();
    const int off = bsum[blockIdx.x] + sh[t] - p;  // exclusive within block
    if (i0 < N_NODES) row_ptr[i0] = off;
    if (i1 < N_NODES) row_ptr[i1] = off + d0;
}

__global__ void k_fill(const int* __restrict__ src, const int* __restrict__ dst,
                       const int* __restrict__ rid, const int* __restrict__ row_ptr,
                       int* __restrict__ cur, int* __restrict__ srcrid)
{
    const int e = blockIdx.x * 256 + threadIdx.x;
    if (e >= N_EDGES) return;
    const int d = dst[e];
    const int pos = row_ptr[d] + atomicAdd(&cur[d], 1);
    srcrid[pos] = src[e] * 64 + rid[e];
}

// ---------------------------------------------------------------------------
// x0 = bf16( node_emb[ids] @ lin_w^T + lin_b )
// ---------------------------------------------------------------------------
__global__ __launch_bounds__(256) void k_lin(
    const float* __restrict__ emb, const int* __restrict__ ids,
    const u16* __restrict__ w, const u16* __restrict__ bias,
    u16* __restrict__ out)
{
    const int wid = threadIdx.x >> 6, lane = threadIdx.x & 63;
    const int r15 = lane & 15, kg = (lane >> 4) * 8;
    const int arow = blockIdx.x * 64 + wid * 16 + r15;
    const int srow = ids[arow];
    const float* ar = emb + (size_t)srow * EMB + kg;
    short8 a[4];
    #pragma unroll
    for (int kk = 0; kk < 4; ++kk) {
        f32x4 a0 = *(const f32x4*)(ar + kk * 32);
        f32x4 a1 = *(const f32x4*)(ar + kk * 32 + 4);
        short8 t;
        #pragma unroll
        for (int j = 0; j < 4; ++j) { t[j] = (short)f2bf(a0[j]); t[4 + j] = (short)f2bf(a1[j]); }
        a[kk] = t;
    }
    f32x4 acc[8];
    #pragma unroll
    for (int nb = 0; nb < 8; ++nb) acc[nb] = (f32x4){0.f, 0.f, 0.f, 0.f};
    #pragma unroll
    for (int nb = 0; nb < 8; ++nb) {
        const u16* wr = w + (size_t)(nb * 16 + r15) * EMB + kg;
        #pragma unroll
        for (int kk = 0; kk < 4; ++kk) {
            short8 bv = *(const short8*)(wr + kk * 32);
            acc[nb] = __builtin_amdgcn_mfma_f32_16x16x32_bf16(a[kk], bv, acc[nb], 0, 0, 0);
        }
    }
    const int ob = blockIdx.x * 64 + wid * 16 + (lane >> 4) * 4;
    #pragma unroll
    for (int nb = 0; nb < 8; ++nb) {
        const int col = nb * 16 + r15;
        const float bn = bf2f(bias[col]);
        #pragma unroll
        for (int r = 0; r < 4; ++r)
            out[(size_t)(ob + r) * HID + col] = f2bf(acc[nb][r] + bn);
    }
}

// ---------------------------------------------------------------------------
// CSR gather-aggregate: agg[n][c] = sum_{p in row n} relu(x[src_p][c] + rel[rid_p][c])
// block = 64 nodes; thread = (node, 32-channel quad-chunk)
// rel_lin staged in LDS with stride 132 (pad 4 f32 -> b128-friendly, ~2-way banks)
// ---------------------------------------------------------------------------
#define RLD 132
__global__ __launch_bounds__(256) void k_agg(
    const u16* __restrict__ x, const float* __restrict__ rel_lin,
    const int* __restrict__ row_ptr, const int* __restrict__ srcrid,
    float* __restrict__ agg)
{
    __shared__ float rel[N_RELS * RLD];
    {   // stage rel_lin: thread t loads row (t>>2), cols (t&3)*32..+31
        const int rr = threadIdx.x >> 2, qq = (threadIdx.x & 3) * 32;
        #pragma unroll
        for (int c = 0; c < 32; c += 4) {
            f32x4 v = *(const f32x4*)(rel_lin + rr * HID + qq + c);
            *(f32x4*)(&rel[rr * RLD + qq + c]) = v;
        }
    }
    __syncthreads();

    const int n = blockIdx.x * 64 + (threadIdx.x >> 2);
    const int q = (threadIdx.x & 3) * 32;
    const int pbeg = row_ptr[n], pend = row_ptr[n + 1];

    float acc[32];
    #pragma unroll
    for (int j = 0; j < 32; ++j) acc[j] = 0.f;

    for (int p = pbeg; p < pend; ++p) {
        const int v = srcrid[p];
        const int s = v >> 6, r = v & 63;
        const u16* xp = x + (size_t)s * HID + q;
        const float* rp = &rel[r * RLD + q];
        #pragma unroll
        for (int c = 0; c < 4; ++c) {
            short8 xv = *(const short8*)(xp + c * 8);
            #pragma unroll
            for (int j = 0; j < 8; ++j)
                acc[c * 8 + j] += fmaxf(bf2f((u16)xv[j]) + rp[c * 8 + j], 0.f);
        }
    }

    float* ap = agg + (size_t)n * HID + q;
    #pragma unroll
    for (int c = 0; c < 8; ++c)
        *(f32x4*)(ap + c * 4) = (f32x4){acc[c * 4], acc[c * 4 + 1], acc[c * 4 + 2], acc[c * 4 + 3]};
}

// ---------------------------------------------------------------------------
// conv GEMM: out = act( bf16(agg + x) @ w^T + b )
// ---------------------------------------------------------------------------
__global__ __launch_bounds__(256) void k_conv(
    const float* __restrict__ agg, const u16* __restrict__ x,
    const u16* __restrict__ w, const u16* __restrict__ bias,
    u16* __restrict__ out, const int do_relu)
{
    const int wid = threadIdx.x >> 6, lane = threadIdx.x & 63;
    const int r15 = lane & 15, kg = (lane >> 4) * 8;
    const int arow = blockIdx.x * 64 + wid * 16 + r15;
    const float* ar = agg + (size_t)arow * HID + kg;
    const u16* xr = x + (size_t)arow * HID + kg;
    short8 a[4];
    #pragma unroll
    for (int kk = 0; kk < 4; ++kk) {
        f32x4 g0 = *(const f32x4*)(ar + kk * 32);
        f32x4 g1 = *(const f32x4*)(ar + kk * 32 + 4);
        short8 xv = *(const short8*)(xr + kk * 32);
        short8 t;
        #pragma unroll
        for (int j = 0; j < 4; ++j) t[j] = (short)f2bf(g0[j] + bf2f((u16)xv[j]));
        #pragma unroll
        for (int j = 0; j < 4; ++j) t[4 + j] = (short)f2bf(g1[j] + bf2f((u16)xv[4 + j]));
        a[kk] = t;
    }
    f32x4 acc[8];
    #pragma unroll
    for (int nb = 0; nb < 8; ++nb) acc[nb] = (f32x4){0.f, 0.f, 0.f, 0.f};
    #pragma unroll
    for (int nb = 0; nb < 8; ++nb) {
        const u16* wr = w + (size_t)(nb * 16 + r15) * HID + kg;
        #pragma unroll
        for (int kk = 0; kk < 4; ++kk) {
            short8 bv = *(const short8*)(wr + kk * 32);
            acc[nb] = __builtin_amdgcn_mfma_f32_16x16x32_bf16(a[kk], bv, acc[nb], 0, 0, 0);
        }
    }
    const int ob = blockIdx.x * 64 + wid * 16 + (lane >> 4) * 4;
    #pragma unroll
    for (int nb = 0; nb < 8; ++nb) {
        const int col = nb * 16 + r15;
        const float bn = bf2f(bias[col]);
        #pragma unroll
        for (int r = 0; r < 4; ++r) {
            float v = acc[nb][r] + bn;
            if (do_relu) v = fmaxf(v, 0.f);
            out[(size_t)(ob + r) * HID + col] = f2bf(v);
        }
    }
}

// ---------------------------------------------------------------------------
// edge head (f32 out)
// ---------------------------------------------------------------------------
__global__ __launch_bounds__(256) void k_edge(
    const u16* __restrict__ x2, const int* __restrict__ src, const int* __restrict__ dst,
    const u16* __restrict__ ew, const u16* __restrict__ eb, float* __restrict__ out)
{
    const int wid = threadIdx.x >> 6, lane = threadIdx.x & 63;
    const int r15 = lane & 15, kg = (lane >> 4) * 8;
    const int erow = blockIdx.x * 64 + wid * 16 + r15;
    const int s = src[erow], d = dst[erow];
    const u16* xs = x2 + (size_t)s * HID + kg;
    const u16* xd = x2 + (size_t)d * HID + kg;
    short8 a[8];
    #pragma unroll
    for (int kk = 0; kk < 4; ++kk) a[kk] = *(const short8*)(xs + kk * 32);
    #pragma unroll
    for (int kk = 0; kk < 4; ++kk) a[4 + kk] = *(const short8*)(xd + kk * 32);
    f32x4 acc[4];
    #pragma unroll
    for (int nb = 0; nb < 4; ++nb) acc[nb] = (f32x4){0.f, 0.f, 0.f, 0.f};
    #pragma unroll
    for (int nb = 0; nb < 4; ++nb) {
        const u16* wr = ew + (size_t)(nb * 16 + r15) * 256 + kg;
        #pragma unroll
        for (int kk = 0; kk < 8; ++kk) {
            short8 bv = *(const short8*)(wr + kk * 32);
            acc[nb] = __builtin_amdgcn_mfma_f32_16x16x32_bf16(a[kk], bv, acc[nb], 0, 0, 0);
        }
    }
    const int ob = blockIdx.x * 64 + wid * 16 + (lane >> 4) * 4;
    #pragma unroll
    for (int nb = 0; nb < 4; ++nb) {
        const int col = nb * 16 + r15;
        const float bn = bf2f(eb[col]);
        #pragma unroll
        for (int r = 0; r < 4; ++r)
            out[(size_t)(ob + r) * 64 + col] = acc[nb][r] + bn;
    }
}

// ---------------------------------------------------------------------------
__global__ void k_motif(const u16* __restrict__ x2, const int* __restrict__ centers,
                        const u16* __restrict__ mw, const u16* __restrict__ mb,
                        float* __restrict__ out)
{
    __shared__ float xs[HID];
    const int c = blockIdx.x, m = threadIdx.x;
    if (m < HID) xs[m] = bf2f(x2[(size_t)centers[c] * HID + m]);
    __syncthreads();
    const u16* wr = mw + (size_t)m * HID;
    float acc = bf2f(mb[m]);
    #pragma unroll
    for (int k0 = 0; k0 < HID; k0 += 8) {
        short8 wv = *(const short8*)(wr + k0);
        #pragma unroll
        for (int j = 0; j < 8; ++j) acc += xs[k0 + j] * bf2f((u16)wv[j]);
    }
    out[(size_t)c * N_MOTIFS + m] = acc;
}

// ---------------------------------------------------------------------------
__global__ __launch_bounds__(256) void k_node(
    const u16* __restrict__ x2, const u16* __restrict__ nw,
    const u16* __restrict__ nbias, float* __restrict__ out)
{
    const int wid = threadIdx.x >> 6, lane = threadIdx.x & 63;
    const int r15 = lane & 15, kg = (lane >> 4) * 8;
    const int arow = blockIdx.x * 64 + wid * 16 + r15;
    const u16* xr = x2 + (size_t)arow * HID + kg;
    const u16* wr = nw + (size_t)r15 * HID + kg;
    f32x4 acc = (f32x4){0.f, 0.f, 0.f, 0.f};
    #pragma unroll
    for (int kk = 0; kk < 4; ++kk) {
        short8 a = *(const short8*)(xr + kk * 32);
        short8 bv = *(const short8*)(wr + kk * 32);
        acc = __builtin_amdgcn_mfma_f32_16x16x32_bf16(a, bv, acc, 0, 0, 0);
    }
    const int ob = blockIdx.x * 64 + wid * 16 + (lane >> 4) * 4;
    const float bn = bf2f(nbias[r15]);
    #pragma unroll
    for (int r = 0; r < 4; ++r)
        out[(size_t)(ob + r) * NCLS + r15] = acc[r] + bn;
}

// ---------------------------------------------------------------------------
extern "C" void kernel_launch(void* const* d_in, const int* in_sizes, int n_in,
                              void* d_out, int out_size, void* d_ws, size_t ws_size,
                              hipStream_t stream)
{
    const float* node_emb = (const float*)d_in[0];
    const float* rel_emb  = (const float*)d_in[1];
    const float* lin_w    = (const float*)d_in[2];
    const float* lin_b    = (const float*)d_in[3];
    const float* conv1_w  = (const float*)d_in[4];
    const float* conv1_b  = (const float*)d_in[5];
    const float* conv2_w  = (const float*)d_in[6];
    const float* conv2_b  = (const float*)d_in[7];
    const float* edge_w   = (const float*)d_in[8];
    const float* edge_b   = (const float*)d_in[9];
    const float* motif_w  = (const float*)d_in[10];
    const float* motif_b  = (const float*)d_in[11];
    const float* node_w   = (const float*)d_in[12];
    const float* node_b   = (const float*)d_in[13];
    const int* node_ids = (const int*)d_in[14];
    const int* rel_ids  = (const int*)d_in[15];
    const int* centers  = (const int*)d_in[16];
    const int* src      = (const int*)d_in[17];             // edge_index[0]
    const int* dst      = ((const int*)d_in[17]) + N_EDGES; // edge_index[1]

    // workspace layout (~210.1 MB):
    char* ws = (char*)d_ws;
    float* rel_lin = (float*)ws;                                  // 32 KB
    u16*   wb      = (u16*)(ws + 32768);                          // 268 KB
    u16*   x0      = (u16*)(ws + 524288);                         // 51.2 MB
    u16*   x1      = (u16*)(ws + 524288 + 51200000);              // 51.2 MB
    float* agg     = (float*)(ws + 524288 + 2 * 51200000);        // 102.4 MB
    char*  csr     = ws + 524288 + 2 * 51200000 + 102400000;
    int*   deg     = (int*)csr;                                   // 800 KB
    int*   cur     = (int*)(csr + 800000);                        // 800 KB
    int*   row_ptr = (int*)(csr + 1600000);                       // 800 KB (+4)
    int*   srcrid  = (int*)(csr + 2400032);                       // 2.4 MB
    int*   bsum    = (int*)(csr + 4800032);                       // 4 KB
    u16*   x2      = x0;

    float* out_edge  = (float*)d_out;                            // [600000][64]
    float* out_motif = out_edge + (size_t)N_EDGES * 64;          // [256][512]
    float* out_node  = out_motif + (size_t)N_CENTERS * N_MOTIFS; // [200000][16]

    k_cvt<<<(N_WB + 255) / 256, 256, 0, stream>>>(
        lin_w, lin_b, conv1_w, conv1_b, conv2_w, conv2_b,
        edge_w, edge_b, motif_w, motif_b, node_w, node_b, wb);
    hipMemsetAsync(deg, 0, 1600000, stream);   // deg + cur together
    k_rel<<<N_RELS, 128, 0, stream>>>(rel_emb, lin_w, lin_b, rel_lin);

    // CSR build
    k_hist<<<(N_EDGES + 255) / 256, 256, 0, stream>>>(dst, deg);
    k_scan1<<<NB_SCAN, 256, 0, stream>>>(deg, bsum);
    k_scan2<<<1, 512, 0, stream>>>(bsum, row_ptr);
    k_scan3<<<NB_SCAN, 256, 0, stream>>>(deg, bsum, row_ptr);
    k_fill<<<(N_EDGES + 255) / 256, 256, 0, stream>>>(src, dst, rel_ids, row_ptr, cur, srcrid);

    k_lin<<<N_NODES / 64, 256, 0, stream>>>(node_emb, node_ids, wb + O_LINW, wb + O_LINB, x0);
    k_agg<<<N_NODES / 64, 256, 0, stream>>>(x0, rel_lin, row_ptr, srcrid, agg);
    k_conv<<<N_NODES / 64, 256, 0, stream>>>(agg, x0, wb + O_C1W, wb + O_C1B, x1, 1);
    k_agg<<<N_NODES / 64, 256, 0, stream>>>(x1, rel_lin, row_ptr, srcrid, agg);
    k_conv<<<N_NODES / 64, 256, 0, stream>>>(agg, x1, wb + O_C2W, wb + O_C2B, x2, 0);
    k_edge<<<N_EDGES / 64, 256, 0, stream>>>(x2, src, dst, wb + O_EW, wb + O_EB, out_edge);
    k_motif<<<N_CENTERS, N_MOTIFS, 0, stream>>>(x2, centers, wb + O_MW, wb + O_MB, out_motif);
    k_node<<<N_NODES / 64, 256, 0, stream>>>(x2, wb + O_NW, wb + O_NB, out_node);
}

// Round 4
// 508.035 us; speedup vs baseline: 4.8407x; 1.2114x over previous
//
#include <hip/hip_runtime.h>
#include <hip/hip_bf16.h>

#define N_NODES 200000
#define N_EDGES 600000
#define EMB 128
#define HID 128
#define N_RELS 64
#define N_MOTIFS 512
#define N_CENTERS 256
#define NCLS 16

#define SCAN_C 512
#define NB_SCAN ((N_NODES + SCAN_C - 1) / SCAN_C)   // 391

typedef unsigned short u16;
typedef __attribute__((ext_vector_type(8))) short short8;   // 8 x bf16
typedef __attribute__((ext_vector_type(4))) float f32x4;

__device__ __forceinline__ float bf2f(u16 u) {
    unsigned int i = ((unsigned int)u) << 16;
    float f; __builtin_memcpy(&f, &i, 4); return f;
}
__device__ __forceinline__ u16 f2bf(float f) {
    unsigned int x; __builtin_memcpy(&x, &f, 4);
    x += 0x7fffu + ((x >> 16) & 1u);          // RNE
    return (u16)(x >> 16);
}

// bf16 weight-table offsets (elements) inside ws
#define O_LINW   0
#define O_LINB   16384
#define O_C1W    16512
#define O_C1B    32896
#define O_C2W    33024
#define O_C2B    49408
#define O_EW     49536
#define O_EB     65920
#define O_MW     65984
#define O_MB     131520
#define O_NW     132032
#define O_NB     134080
#define N_WB     134096

// ---------------------------------------------------------------------------
__global__ void k_cvt(const float* __restrict__ lw, const float* __restrict__ lb,
                      const float* __restrict__ c1w, const float* __restrict__ c1b,
                      const float* __restrict__ c2w, const float* __restrict__ c2b,
                      const float* __restrict__ ew, const float* __restrict__ eb,
                      const float* __restrict__ mw, const float* __restrict__ mb,
                      const float* __restrict__ nw, const float* __restrict__ nb,
                      u16* __restrict__ wb)
{
    const int t = blockIdx.x * 256 + threadIdx.x;
    if (t >= N_WB) return;
    float v;
    if      (t < O_LINB) v = lw[t - O_LINW];
    else if (t < O_C1W)  v = lb[t - O_LINB];
    else if (t < O_C1B)  v = c1w[t - O_C1W];
    else if (t < O_C2W)  v = c1b[t - O_C1B];
    else if (t < O_C2B)  v = c2w[t - O_C2W];
    else if (t < O_EW)   v = c2b[t - O_C2B];
    else if (t < O_EB)   v = ew[t - O_EW];
    else if (t < O_MW)   v = eb[t - O_EB];
    else if (t < O_MB)   v = mw[t - O_MW];
    else if (t < O_NW)   v = mb[t - O_MB];
    else if (t < O_NB)   v = nw[t - O_NW];
    else                 v = nb[t - O_NB];
    wb[t] = f2bf(v);
}

// ---------------------------------------------------------------------------
// rel_lin[r][h] = rel_emb[r] . lin_w[h] + lin_b[h]   (all f32)
// ---------------------------------------------------------------------------
__global__ void k_rel(const float* __restrict__ rel_emb, const float* __restrict__ lw,
                      const float* __restrict__ lb, float* __restrict__ rel_lin)
{
    __shared__ float e[EMB];
    const int r = blockIdx.x, h = threadIdx.x;
    e[h] = rel_emb[r * EMB + h];
    __syncthreads();
    const float* wr = lw + (size_t)h * EMB;
    float acc = lb[h];
    #pragma unroll
    for (int k0 = 0; k0 < EMB; k0 += 4) {
        f32x4 wv = *(const f32x4*)(wr + k0);
        #pragma unroll
        for (int j = 0; j < 4; ++j) acc += e[k0 + j] * wv[j];
    }
    rel_lin[r * HID + h] = acc;
}

// ---------------------------------------------------------------------------
// CSR build
// ---------------------------------------------------------------------------
__global__ void k_hist(const int* __restrict__ dst, int* __restrict__ deg)
{
    const int e = blockIdx.x * 256 + threadIdx.x;
    if (e < N_EDGES) atomicAdd(&deg[dst[e]], 1);
}

__global__ void k_scan1(const int* __restrict__ deg, int* __restrict__ bsum)
{
    __shared__ int sd[256];
    const int t = threadIdx.x, base = blockIdx.x * SCAN_C;
    int v = 0;
    int i0 = base + t, i1 = base + 256 + t;
    if (i0 < N_NODES) v += deg[i0];
    if (i1 < N_NODES) v += deg[i1];
    sd[t] = v; __syncthreads();
    for (int s = 128; s > 0; s >>= 1) {
        if (t < s) sd[t] += sd[t + s];
        __syncthreads();
    }
    if (t == 0) bsum[blockIdx.x] = sd[0];
}

__global__ void k_scan2(int* __restrict__ bsum, int* __restrict__ row_ptr)
{
    __shared__ int sh[512];
    const int t = threadIdx.x;
    int v = (t < NB_SCAN) ? bsum[t] : 0;
    sh[t] = v;
    for (int off = 1; off < 512; off <<= 1) {
        __syncthreads();
        int a = (t >= off) ? sh[t - off] : 0;
        __syncthreads();
        sh[t] += a;
    }
    __syncthreads();
    if (t < NB_SCAN) bsum[t] = sh[t] - v;         // exclusive
    if (t == 511) row_ptr[N_NODES] = sh[511];     // total = E
}

__global__ void k_scan3(const int* __restrict__ deg, const int* __restrict__ bsum,
                        int* __restrict__ row_ptr)
{
    __shared__ int sh[256];
    const int t = threadIdx.x, base = blockIdx.x * SCAN_C;
    const int i0 = base + 2 * t, i1 = i0 + 1;
    int d0 = (i0 < N_NODES) ? deg[i0] : 0;
    int d1 = (i1 < N_NODES) ? deg[i1] : 0;
    int p = d0 + d1;
    sh[t] = p;
    for (int off = 1; off < 256; off <<= 1) {
        __syncthreads();
        int a = (t >= off) ? sh[t - off] : 0;
        __syncthreads();
        sh[t] += a;
    }
    __syncthreads();
    const int off = bsum[blockIdx.x] + sh[t] - p;  // exclusive within block
    if (i0 < N_NODES) row_ptr[i0] = off;
    if (i1 < N_NODES) row_ptr[i1] = off + d0;
}

__global__ void k_fill(const int* __restrict__ src, const int* __restrict__ dst,
                       const int* __restrict__ rid, const int* __restrict__ row_ptr,
                       int* __restrict__ cur, int* __restrict__ srcrid)
{
    const int e = blockIdx.x * 256 + threadIdx.x;
    if (e >= N_EDGES) return;
    const int d = dst[e];
    const int pos = row_ptr[d] + atomicAdd(&cur[d], 1);
    srcrid[pos] = src[e] * 64 + rid[e];
}

// ---------------------------------------------------------------------------
// x0 = bf16( node_emb[ids] @ lin_w^T + lin_b )
// ---------------------------------------------------------------------------
__global__ __launch_bounds__(256) void k_lin(
    const float* __restrict__ emb, const int* __restrict__ ids,
    const u16* __restrict__ w, const u16* __restrict__ bias,
    u16* __restrict__ out)
{
    const int wid = threadIdx.x >> 6, lane = threadIdx.x & 63;
    const int r15 = lane & 15, kg = (lane >> 4) * 8;
    const int arow = blockIdx.x * 64 + wid * 16 + r15;
    const int srow = ids[arow];
    const float* ar = emb + (size_t)srow * EMB + kg;
    short8 a[4];
    #pragma unroll
    for (int kk = 0; kk < 4; ++kk) {
        f32x4 a0 = *(const f32x4*)(ar + kk * 32);
        f32x4 a1 = *(const f32x4*)(ar + kk * 32 + 4);
        short8 t;
        #pragma unroll
        for (int j = 0; j < 4; ++j) { t[j] = (short)f2bf(a0[j]); t[4 + j] = (short)f2bf(a1[j]); }
        a[kk] = t;
    }
    f32x4 acc[8];
    #pragma unroll
    for (int nb = 0; nb < 8; ++nb) acc[nb] = (f32x4){0.f, 0.f, 0.f, 0.f};
    #pragma unroll
    for (int nb = 0; nb < 8; ++nb) {
        const u16* wr = w + (size_t)(nb * 16 + r15) * EMB + kg;
        #pragma unroll
        for (int kk = 0; kk < 4; ++kk) {
            short8 bv = *(const short8*)(wr + kk * 32);
            acc[nb] = __builtin_amdgcn_mfma_f32_16x16x32_bf16(a[kk], bv, acc[nb], 0, 0, 0);
        }
    }
    const int ob = blockIdx.x * 64 + wid * 16 + (lane >> 4) * 4;
    #pragma unroll
    for (int nb = 0; nb < 8; ++nb) {
        const int col = nb * 16 + r15;
        const float bn = bf2f(bias[col]);
        #pragma unroll
        for (int r = 0; r < 4; ++r)
            out[(size_t)(ob + r) * HID + col] = f2bf(acc[nb][r] + bn);
    }
}

// ---------------------------------------------------------------------------
// FUSED agg + conv:
//   phase 1: quad-per-node CSR gather  acc[c] = sum relu(x[src]+rel[rid])
//            then bf16(acc + x[n]) -> LDS tile (pad 136 for alignment/banks)
//   phase 2: MFMA  out = act( tile @ w^T + b )
// ---------------------------------------------------------------------------
#define RLD 132
#define ALD 136
__global__ __launch_bounds__(256) void k_fuse(
    const u16* __restrict__ x, const float* __restrict__ rel_lin,
    const int* __restrict__ row_ptr, const int* __restrict__ srcrid,
    const u16* __restrict__ w, const u16* __restrict__ bias,
    u16* __restrict__ out, const int do_relu)
{
    __shared__ float rel[N_RELS * RLD];   // 33.8 KB
    __shared__ u16 atile[64 * ALD];       // 17.4 KB
    {   // stage rel_lin
        const int rr = threadIdx.x >> 2, qq = (threadIdx.x & 3) * 32;
        #pragma unroll
        for (int c = 0; c < 32; c += 4) {
            f32x4 v = *(const f32x4*)(rel_lin + rr * HID + qq + c);
            *(f32x4*)(&rel[rr * RLD + qq + c]) = v;
        }
    }
    __syncthreads();

    // ---- phase 1: gather-aggregate ----
    const int nl = threadIdx.x >> 2;              // 0..63 local node
    const int n = blockIdx.x * 64 + nl;
    const int q = (threadIdx.x & 3) * 32;
    const int pbeg = row_ptr[n], pend = row_ptr[n + 1];

    float acc[32];
    #pragma unroll
    for (int j = 0; j < 32; ++j) acc[j] = 0.f;

    for (int p = pbeg; p < pend; ++p) {
        const int v = srcrid[p];
        const int s = v >> 6, r = v & 63;
        const u16* xp = x + (size_t)s * HID + q;
        const float* rp = &rel[r * RLD + q];
        #pragma unroll
        for (int c = 0; c < 4; ++c) {
            short8 xv = *(const short8*)(xp + c * 8);
            #pragma unroll
            for (int j = 0; j < 8; ++j)
                acc[c * 8 + j] += fmaxf(bf2f((u16)xv[j]) + rp[c * 8 + j], 0.f);
        }
    }
    {   // add own x row, convert, stash in LDS
        const u16* xp = x + (size_t)n * HID + q;
        #pragma unroll
        for (int c = 0; c < 4; ++c) {
            short8 xv = *(const short8*)(xp + c * 8);
            short8 t;
            #pragma unroll
            for (int j = 0; j < 8; ++j) t[j] = (short)f2bf(acc[c * 8 + j] + bf2f((u16)xv[j]));
            *(short8*)(&atile[nl * ALD + q + c * 8]) = t;
        }
    }
    __syncthreads();

    // ---- phase 2: MFMA conv ----
    const int wid = threadIdx.x >> 6, lane = threadIdx.x & 63;
    const int r15 = lane & 15, kg = (lane >> 4) * 8;
    const int lrow = wid * 16 + r15;
    short8 a[4];
    #pragma unroll
    for (int kk = 0; kk < 4; ++kk) a[kk] = *(const short8*)(&atile[lrow * ALD + kg + kk * 32]);
    f32x4 accm[8];
    #pragma unroll
    for (int nb = 0; nb < 8; ++nb) accm[nb] = (f32x4){0.f, 0.f, 0.f, 0.f};
    #pragma unroll
    for (int nb = 0; nb < 8; ++nb) {
        const u16* wr = w + (size_t)(nb * 16 + r15) * HID + kg;
        #pragma unroll
        for (int kk = 0; kk < 4; ++kk) {
            short8 bv = *(const short8*)(wr + kk * 32);
            accm[nb] = __builtin_amdgcn_mfma_f32_16x16x32_bf16(a[kk], bv, accm[nb], 0, 0, 0);
        }
    }
    const int ob = blockIdx.x * 64 + wid * 16 + (lane >> 4) * 4;
    #pragma unroll
    for (int nb = 0; nb < 8; ++nb) {
        const int col = nb * 16 + r15;
        const float bn = bf2f(bias[col]);
        #pragma unroll
        for (int r = 0; r < 4; ++r) {
            float v = accm[nb][r] + bn;
            if (do_relu) v = fmaxf(v, 0.f);
            out[(size_t)(ob + r) * HID + col] = f2bf(v);
        }
    }
}

// ---------------------------------------------------------------------------
// heads precompute: per 64 nodes, A-frags from x2 (global, coalesced);
//   y[n][0:64]   = x2[n] . ew[:, 0:128]    (f32, no bias)
//   y[n][64:128] = x2[n] . ew[:, 128:256]
//   node_out[n]  = x2[n] . nw + nb
// ---------------------------------------------------------------------------
__global__ __launch_bounds__(256) void k_heads(
    const u16* __restrict__ x2, const u16* __restrict__ ew,
    const u16* __restrict__ nw, const u16* __restrict__ nbias,
    float* __restrict__ y, float* __restrict__ node_out)
{
    const int wid = threadIdx.x >> 6, lane = threadIdx.x & 63;
    const int r15 = lane & 15, kg = (lane >> 4) * 8;
    const int arow = blockIdx.x * 64 + wid * 16 + r15;
    const u16* xr = x2 + (size_t)arow * HID + kg;
    short8 a[4];
    #pragma unroll
    for (int kk = 0; kk < 4; ++kk) a[kk] = *(const short8*)(xr + kk * 32);

    f32x4 accs[4], accd[4], accn;
    #pragma unroll
    for (int nb = 0; nb < 4; ++nb) {
        accs[nb] = (f32x4){0.f, 0.f, 0.f, 0.f};
        accd[nb] = (f32x4){0.f, 0.f, 0.f, 0.f};
    }
    accn = (f32x4){0.f, 0.f, 0.f, 0.f};

    #pragma unroll
    for (int nb = 0; nb < 4; ++nb) {
        const u16* wr = ew + (size_t)(nb * 16 + r15) * 256 + kg;
        #pragma unroll
        for (int kk = 0; kk < 4; ++kk) {
            short8 bs = *(const short8*)(wr + kk * 32);
            short8 bd = *(const short8*)(wr + 128 + kk * 32);
            accs[nb] = __builtin_amdgcn_mfma_f32_16x16x32_bf16(a[kk], bs, accs[nb], 0, 0, 0);
            accd[nb] = __builtin_amdgcn_mfma_f32_16x16x32_bf16(a[kk], bd, accd[nb], 0, 0, 0);
        }
    }
    {
        const u16* wr = nw + (size_t)r15 * HID + kg;
        #pragma unroll
        for (int kk = 0; kk < 4; ++kk) {
            short8 bv = *(const short8*)(wr + kk * 32);
            accn = __builtin_amdgcn_mfma_f32_16x16x32_bf16(a[kk], bv, accn, 0, 0, 0);
        }
    }

    const int ob = blockIdx.x * 64 + wid * 16 + (lane >> 4) * 4;
    #pragma unroll
    for (int nb = 0; nb < 4; ++nb) {
        const int col = nb * 16 + r15;
        #pragma unroll
        for (int r = 0; r < 4; ++r) {
            y[(size_t)(ob + r) * 128 + col] = accs[nb][r];
            y[(size_t)(ob + r) * 128 + 64 + col] = accd[nb][r];
        }
    }
    const float bn = bf2f(nbias[r15]);
    #pragma unroll
    for (int r = 0; r < 4; ++r)
        node_out[(size_t)(ob + r) * NCLS + r15] = accn[r] + bn;
}

// ---------------------------------------------------------------------------
// edge output: out[e][c] = y[src[e]][c] + y[dst[e]][64+c] + eb[c]
// 4 threads/edge, 16 f32 each; coalesced writes
// ---------------------------------------------------------------------------
__global__ __launch_bounds__(256) void k_eout(
    const float* __restrict__ y, const int* __restrict__ src, const int* __restrict__ dst,
    const float* __restrict__ eb, float* __restrict__ out)
{
    const int t = blockIdx.x * 256 + threadIdx.x;
    const int e = t >> 2;
    const int qq = (t & 3) * 16;
    const int s = src[e], d = dst[e];
    const float* ys = y + (size_t)s * 128 + qq;
    const float* yd = y + (size_t)d * 128 + 64 + qq;
    const float* ebp = eb + qq;
    float* op = out + (size_t)e * 64 + qq;
    #pragma unroll
    for (int c = 0; c < 4; ++c) {
        f32x4 vs = *(const f32x4*)(ys + c * 4);
        f32x4 vd = *(const f32x4*)(yd + c * 4);
        f32x4 vb = *(const f32x4*)(ebp + c * 4);
        f32x4 r;
        #pragma unroll
        for (int j = 0; j < 4; ++j) r[j] = vs[j] + vd[j] + vb[j];
        *(f32x4*)(op + c * 4) = r;
    }
}

// ---------------------------------------------------------------------------
__global__ void k_motif(const u16* __restrict__ x2, const int* __restrict__ centers,
                        const u16* __restrict__ mw, const u16* __restrict__ mb,
                        float* __restrict__ out)
{
    __shared__ float xs[HID];
    const int c = blockIdx.x, m = threadIdx.x;
    if (m < HID) xs[m] = bf2f(x2[(size_t)centers[c] * HID + m]);
    __syncthreads();
    const u16* wr = mw + (size_t)m * HID;
    float acc = bf2f(mb[m]);
    #pragma unroll
    for (int k0 = 0; k0 < HID; k0 += 8) {
        short8 wv = *(const short8*)(wr + k0);
        #pragma unroll
        for (int j = 0; j < 8; ++j) acc += xs[k0 + j] * bf2f((u16)wv[j]);
    }
    out[(size_t)c * N_MOTIFS + m] = acc;
}

// ---------------------------------------------------------------------------
extern "C" void kernel_launch(void* const* d_in, const int* in_sizes, int n_in,
                              void* d_out, int out_size, void* d_ws, size_t ws_size,
                              hipStream_t stream)
{
    const float* node_emb = (const float*)d_in[0];
    const float* rel_emb  = (const float*)d_in[1];
    const float* lin_w    = (const float*)d_in[2];
    const float* lin_b    = (const float*)d_in[3];
    const float* conv1_w  = (const float*)d_in[4];
    const float* conv1_b  = (const float*)d_in[5];
    const float* conv2_w  = (const float*)d_in[6];
    const float* conv2_b  = (const float*)d_in[7];
    const float* edge_w   = (const float*)d_in[8];
    const float* edge_b   = (const float*)d_in[9];
    const float* motif_w  = (const float*)d_in[10];
    const float* motif_b  = (const float*)d_in[11];
    const float* node_w   = (const float*)d_in[12];
    const float* node_b   = (const float*)d_in[13];
    const int* node_ids = (const int*)d_in[14];
    const int* rel_ids  = (const int*)d_in[15];
    const int* centers  = (const int*)d_in[16];
    const int* src      = (const int*)d_in[17];             // edge_index[0]
    const int* dst      = ((const int*)d_in[17]) + N_EDGES; // edge_index[1]

    // workspace layout (~210 MB, same footprint as round 3):
    char* ws = (char*)d_ws;
    float* rel_lin = (float*)ws;                                  // 32 KB
    u16*   wb      = (u16*)(ws + 32768);                          // 268 KB
    u16*   x0      = (u16*)(ws + 524288);                         // 51.2 MB
    u16*   x1      = (u16*)(ws + 524288 + 51200000);              // 51.2 MB
    float* y       = (float*)(ws + 524288 + 2 * 51200000);        // 102.4 MB (was agg)
    char*  csr     = ws + 524288 + 2 * 51200000 + 102400000;
    int*   deg     = (int*)csr;                                   // 800 KB
    int*   cur     = (int*)(csr + 800000);                        // 800 KB
    int*   row_ptr = (int*)(csr + 1600000);                       // 800 KB (+4)
    int*   srcrid  = (int*)(csr + 2400032);                       // 2.4 MB
    int*   bsum    = (int*)(csr + 4800032);                       // 4 KB
    u16*   x2      = x0;

    float* out_edge  = (float*)d_out;                            // [600000][64]
    float* out_motif = out_edge + (size_t)N_EDGES * 64;          // [256][512]
    float* out_node  = out_motif + (size_t)N_CENTERS * N_MOTIFS; // [200000][16]

    k_cvt<<<(N_WB + 255) / 256, 256, 0, stream>>>(
        lin_w, lin_b, conv1_w, conv1_b, conv2_w, conv2_b,
        edge_w, edge_b, motif_w, motif_b, node_w, node_b, wb);
    hipMemsetAsync(deg, 0, 1600000, stream);   // deg + cur together
    k_rel<<<N_RELS, 128, 0, stream>>>(rel_emb, lin_w, lin_b, rel_lin);

    // CSR build
    k_hist<<<(N_EDGES + 255) / 256, 256, 0, stream>>>(dst, deg);
    k_scan1<<<NB_SCAN, 256, 0, stream>>>(deg, bsum);
    k_scan2<<<1, 512, 0, stream>>>(bsum, row_ptr);
    k_scan3<<<NB_SCAN, 256, 0, stream>>>(deg, bsum, row_ptr);
    k_fill<<<(N_EDGES + 255) / 256, 256, 0, stream>>>(src, dst, rel_ids, row_ptr, cur, srcrid);

    k_lin<<<N_NODES / 64, 256, 0, stream>>>(node_emb, node_ids, wb + O_LINW, wb + O_LINB, x0);
    k_fuse<<<N_NODES / 64, 256, 0, stream>>>(x0, rel_lin, row_ptr, srcrid,
                                             wb + O_C1W, wb + O_C1B, x1, 1);
    k_fuse<<<N_NODES / 64, 256, 0, stream>>>(x1, rel_lin, row_ptr, srcrid,
                                             wb + O_C2W, wb + O_C2B, x2, 0);
    k_heads<<<N_NODES / 64, 256, 0, stream>>>(x2, wb + O_EW, wb + O_NW, wb + O_NB, y, out_node);
    k_eout<<<(N_EDGES * 4) / 256, 256, 0, stream>>>(y, src, dst, edge_b, out_edge);
    k_motif<<<N_CENTERS, N_MOTIFS, 0, stream>>>(x2, centers, wb + O_MW, wb + O_MB, out_motif);
}